// Round 3
// baseline (609.039 us; speedup 1.0000x reference)
//
#include <hip/hip_runtime.h>
#include <hip/hip_bf16.h>

#define D 768
#define NQKV 2304            /* 3*D */
#define NH 12
#define HD 64
#define BATCH 4
#define LSEQ 8190
#define LPAD 8192
#define TP (BATCH*LPAD)      /* 32768 padded tokens */

typedef __bf16 bf16x8 __attribute__((ext_vector_type(8)));
typedef float f32x4 __attribute__((ext_vector_type(4)));
using bf16 = __hip_bfloat16;

__device__ __forceinline__ float b2f(bf16 x){ return __bfloat162float(x); }
__device__ __forceinline__ bf16 f2b(float x){ return __float2bfloat16(x); }
__device__ __forceinline__ f32x4 mfma16(bf16x8 a, bf16x8 b, f32x4 c){
    return __builtin_amdgcn_mfma_f32_16x16x32_bf16(a, b, c, 0, 0, 0);
}
// async global->LDS, 16 B per lane; LDS dest = wave-uniform base + lane*16
__device__ __forceinline__ void gload_lds16(const void* g, void* l){
    __builtin_amdgcn_global_load_lds(
        (const __attribute__((address_space(1))) unsigned int*)g,
        (__attribute__((address_space(3))) unsigned int*)l, 16, 0, 0);
}
template<int N> __device__ __forceinline__ void vwait(){
    asm volatile("s_waitcnt vmcnt(%0)" :: "n"(N) : "memory");
}
__device__ __forceinline__ void lgkm0(){
    asm volatile("s_waitcnt lgkmcnt(0)" ::: "memory");
}

// ---------------------------------------------------------------------------
// Transpose+convert fp32 weights -> bf16 [n][k]. y=0..2 -> WqkvT slices, y=3 -> WoT.
// ---------------------------------------------------------------------------
__global__ void k_transpose(const float* __restrict__ w0, const float* __restrict__ w1,
                            const float* __restrict__ w2, const float* __restrict__ w3,
                            bf16* __restrict__ WqkvT, bf16* __restrict__ WoT) {
    const float* src; bf16* dst;
    switch (blockIdx.y) {
        case 0:  src = w0; dst = WqkvT;               break;
        case 1:  src = w1; dst = WqkvT + D * D;       break;
        case 2:  src = w2; dst = WqkvT + 2 * D * D;   break;
        default: src = w3; dst = WoT;                 break;
    }
    int o = blockIdx.x * 256 + threadIdx.x;   // 0..589823
    int n = o / D, k = o % D;
    dst[o] = f2b(src[k * D + n]);             // dst[n][k] = src[k][n]
}

// ---------------------------------------------------------------------------
// Convert chunk of X (global padded-token indexed) to bf16, pad rows -> 0.
// ---------------------------------------------------------------------------
__global__ __launch_bounds__(256) void k_prep(const float* __restrict__ X,
                                              bf16* __restrict__ Xb, int tok0)
{
    int idx = (blockIdx.x * 256 + threadIdx.x) * 8;  // chunk-local elem
    int row = idx / D, col = idx % D;
    int gt = tok0 + row, b = gt >> 13, pos = gt & 8191;
    bf16 tmp[8];
    if (pos < LSEQ) {
        const float* s = &X[((size_t)b * LSEQ + pos) * D + col];
        float4 f0 = *reinterpret_cast<const float4*>(s);
        float4 f1 = *reinterpret_cast<const float4*>(s + 4);
        tmp[0]=f2b(f0.x); tmp[1]=f2b(f0.y); tmp[2]=f2b(f0.z); tmp[3]=f2b(f0.w);
        tmp[4]=f2b(f1.x); tmp[5]=f2b(f1.y); tmp[6]=f2b(f1.z); tmp[7]=f2b(f1.w);
    } else {
        #pragma unroll
        for (int j = 0; j < 8; ++j) tmp[j] = f2b(0.f);
    }
    *reinterpret_cast<uint4*>(&Xb[idx]) = *reinterpret_cast<const uint4*>(tmp);
}

// ---------------------------------------------------------------------------
// Fused QKV GEMM, 256x256 tile, BK=64, 8 waves (2Mx4N), wave C = 128x64.
// LDS: A[2][256][64], B[2][256][64] (128 KiB dbuf). 4 phases/K-tile, 16 MFMA
// each, B-frags hoisted at p0.
//
// RACE-SAFE BOUNDARY RULE (round-2 fix): vmcnt is per-wave, so every counted
// wait sits BEFORE a trailing s_barrier; only data covered by a prior
// {all-waves vwait + barrier} is ever ds_read. Boundaries:
//   end p1: vwait<4> (retire cur tile A-h1; keep next-tile B stages in flight)
//   end p3: vwait<2> (retire next tile B-h0,B-h1,A-h0; keep A-h1 in flight)
//   last tile: vwait<0> at p1.
// Swizzle: 16B slot s of a 128B row r holds global slot s ^ (r&7), applied on
// the global source (gload_lds writes linearly) and on the ds_read address.
// ---------------------------------------------------------------------------
__global__ __launch_bounds__(512, 2) void k_gemm_qkv(
    const bf16* __restrict__ Xb, const bf16* __restrict__ Wt,
    const float* __restrict__ bq, const float* __restrict__ bk, const float* __restrict__ bv,
    bf16* __restrict__ Qkv)
{
    __shared__ alignas(16) bf16 a_lds[2 * 256 * 64];   // 64 KiB
    __shared__ alignas(16) bf16 b_lds[2 * 256 * 64];   // 64 KiB

    const int tid = threadIdx.x;
    const int wave = tid >> 6, lane = tid & 63, quad = lane >> 4, lm = lane & 15;
    const int wm = wave >> 2, wn = wave & 3;           // 2x4 wave grid

    // XCD-aware bijective swizzle (nwg % 8 == 0 in all chunk configs used)
    int bid = blockIdx.x;
    const int nwg = gridDim.x;
    if ((nwg & 7) == 0) { const int cpx = nwg >> 3; bid = (bid & 7) * cpx + (bid >> 3); }
    const int rt = bid / 9, ct = bid % 9;

    // staging: one gload call = 512 lanes x 16B = 8KB = 64 rows x 128B
    const int srow = tid >> 3;                         // 0..63
    const int ssl  = ((tid & 7) ^ (srow & 7)) * 8;     // pre-swizzled k-slot
    const bf16* a_src = Xb + (size_t)(rt * 256 + srow) * D + ssl;
    const bf16* b_src = Wt + (size_t)(ct * 256 + srow) * D + ssl;
    const int ldsW = wave * 512;                       // wave-uniform dest (elems)

    auto stageA = [&](int T, int h) {                  // rows h*128 .. h*128+127
        bf16* d = a_lds + (T & 1) * 16384 + h * 8192 + ldsW;
        const bf16* s = a_src + (size_t)(h * 128) * D + T * 64;
        gload_lds16(s, d);
        gload_lds16(s + (size_t)64 * D, d + 4096);
    };
    auto stageB = [&](int T, int h) {
        bf16* d = b_lds + (T & 1) * 16384 + h * 8192 + ldsW;
        const bf16* s = b_src + (size_t)(h * 128) * D + T * 64;
        gload_lds16(s, d);
        gload_lds16(s + (size_t)64 * D, d + 4096);
    };

    // swizzled fragment slots (row&7 == lm&7 for all frag rows)
    const int swf0 = ((0 + quad) ^ (lm & 7)) * 8;      // ks = 0
    const int swf1 = ((4 + quad) ^ (lm & 7)) * 8;      // ks = 1
    const int arow0 = wm * 32 + lm;
    const int brow0 = wn * 64 + lm;

    f32x4 acc[8][4] = {};

    // prologue: stage tile 0 (8 loads, order Bh0,Bh1,Ah0,Ah1); retire first 6.
    stageB(0, 0); stageB(0, 1); stageA(0, 0); stageA(0, 1);
    vwait<2>();
    __builtin_amdgcn_s_barrier();

    #pragma unroll
    for (int t = 0; t < 12; ++t) {
        const bf16* ab = a_lds + (t & 1) * 16384;
        const bf16* bb = b_lds + (t & 1) * 16384;
        bf16x8 bfr[4][2];
        #pragma unroll
        for (int p = 0; p < 4; ++p) {
            // ---- fragment ds_reads (covered by earlier vwait+barrier) ----
            bf16x8 af[2][2];
            #pragma unroll
            for (int i = 0; i < 2; ++i) {
                const int r = (p * 64 + arow0 + i * 16) * 64;
                af[i][0] = *reinterpret_cast<const bf16x8*>(&ab[r + swf0]);
                af[i][1] = *reinterpret_cast<const bf16x8*>(&ab[r + swf1]);
            }
            if (p == 0) {
                #pragma unroll
                for (int n = 0; n < 4; ++n) {
                    const int r = (brow0 + n * 16) * 64;
                    bfr[n][0] = *reinterpret_cast<const bf16x8*>(&bb[r + swf0]);
                    bfr[n][1] = *reinterpret_cast<const bf16x8*>(&bb[r + swf1]);
                }
            }
            // ---- stage next tile (other buffer; 2 gloads per phase) ----
            if (t < 11) {
                if (p == 0) stageB(t + 1, 0);
                if (p == 1) stageB(t + 1, 1);
                if (p == 2) stageA(t + 1, 0);
                if (p == 3) stageA(t + 1, 1);
            }
            __builtin_amdgcn_s_barrier();
            lgkm0();
            __builtin_amdgcn_s_setprio(1);
            #pragma unroll
            for (int ks = 0; ks < 2; ++ks)
                #pragma unroll
                for (int i = 0; i < 2; ++i)
                    #pragma unroll
                    for (int n = 0; n < 4; ++n)
                        acc[p * 2 + i][n] = mfma16(af[i][ks], bfr[n][ks], acc[p * 2 + i][n]);
            __builtin_amdgcn_s_setprio(0);
            // ---- boundary waits: BEFORE the trailing barrier ----
            if (p == 1) { if (t < 11) vwait<4>(); else vwait<0>(); }
            if (p == 3 && t < 11) vwait<2>();
            if (!(p == 3 && t == 11)) __builtin_amdgcn_s_barrier();
        }
    }

    // epilogue: bias + bf16 store. ct*256 block lies inside one of q/k/v.
    const float* bias; int cb;
    if (ct < 3)      { bias = bq; cb = ct * 256; }
    else if (ct < 6) { bias = bk; cb = ct * 256 - D; }
    else             { bias = bv; cb = ct * 256 - 2 * D; }
    float bvv[4];
    #pragma unroll
    for (int n = 0; n < 4; ++n)
        bvv[n] = bias[cb + wn * 64 + n * 16 + lm];

    const int col0 = ct * 256 + wn * 64 + lm;
    #pragma unroll
    for (int j = 0; j < 8; ++j)
        #pragma unroll
        for (int reg = 0; reg < 4; ++reg) {
            int row = rt * 256 + (j >> 1) * 64 + wm * 32 + (j & 1) * 16 + quad * 4 + reg;
            size_t rb = (size_t)row * NQKV;
            #pragma unroll
            for (int n = 0; n < 4; ++n)
                Qkv[rb + col0 + n * 16] = f2b(acc[j][n][reg] + bvv[n]);
        }
}

// ---------------------------------------------------------------------------
// Per-(window, head) attention on the interleaved Qkv buffer (stride 2304).
// ---------------------------------------------------------------------------
__global__ __launch_bounds__(256) void k_attn(bf16* Qkv)
{
    __shared__ bf16 qk_lds[2 * 128 * 72];
    __shared__ bf16 vt_lds[64 * 136];
    const int tid = threadIdx.x;
    const int g0 = blockIdx.x * 128, hc = blockIdx.y * 64;
    const int wave = tid >> 6, lane = tid & 63, quad = lane >> 4, lm = lane & 15;
    const int wq = wave * 32;
    bf16* Q_lds = qk_lds;
    bf16* K_lds = qk_lds + 128 * 72;
    bf16* P_lds = qk_lds;                   // overlay after barrier, stride 136

    #pragma unroll
    for (int p = 0; p < 4; ++p) {
        int cid = tid + p * 256;            // 0..1023
        int r = cid >> 3, cc = (cid & 7) * 8;
        size_t rb = (size_t)(g0 + r) * NQKV;
        *reinterpret_cast<uint4*>(&Q_lds[r * 72 + cc]) =
            *reinterpret_cast<const uint4*>(&Qkv[rb + hc + cc]);
        *reinterpret_cast<uint4*>(&K_lds[r * 72 + cc]) =
            *reinterpret_cast<const uint4*>(&Qkv[rb + D + hc + cc]);
        uint4 vv = *reinterpret_cast<const uint4*>(&Qkv[rb + 2 * D + hc + cc]);
        const bf16* ve = reinterpret_cast<const bf16*>(&vv);
        #pragma unroll
        for (int j = 0; j < 8; ++j) vt_lds[(cc + j) * 136 + r] = ve[j];   // V^T
    }
    __syncthreads();

    // S = Q K^T : each wave computes 32 query rows x 128 keys
    f32x4 s[2][8] = {};
    #pragma unroll
    for (int ks = 0; ks < HD; ks += 32) {
        bf16x8 aq[2];
        #pragma unroll
        for (int i = 0; i < 2; ++i)
            aq[i] = *reinterpret_cast<const bf16x8*>(&Q_lds[(wq + i * 16 + lm) * 72 + ks + quad * 8]);
        #pragma unroll
        for (int nt = 0; nt < 8; ++nt) {
            bf16x8 bk = *reinterpret_cast<const bf16x8*>(&K_lds[(nt * 16 + lm) * 72 + ks + quad * 8]);
            s[0][nt] = mfma16(aq[0], bk, s[0][nt]);
            s[1][nt] = mfma16(aq[1], bk, s[1][nt]);
        }
    }
    __syncthreads();   // all Q/K reads done before P overlays them

    const float scale = 0.125f;             // 1/sqrt(64)
    #pragma unroll
    for (int i = 0; i < 2; ++i)
        #pragma unroll
        for (int reg = 0; reg < 4; ++reg) {
            float m = -1e30f;
            #pragma unroll
            for (int nt = 0; nt < 8; ++nt) m = fmaxf(m, s[i][nt][reg]);
            #pragma unroll
            for (int off = 8; off >= 1; off >>= 1) m = fmaxf(m, __shfl_xor(m, off));
            float pv[8]; float sum = 0.f;
            #pragma unroll
            for (int nt = 0; nt < 8; ++nt) {
                float p = __expf((s[i][nt][reg] - m) * scale);
                pv[nt] = p; sum += p;
            }
            #pragma unroll
            for (int off = 8; off >= 1; off >>= 1) sum += __shfl_xor(sum, off);
            float rinv = 1.f / sum;
            int row = wq + i * 16 + quad * 4 + reg;
            #pragma unroll
            for (int nt = 0; nt < 8; ++nt)
                P_lds[row * 136 + nt * 16 + lm] = f2b(pv[nt] * rinv);
        }
    __syncthreads();

    // O = P V
    f32x4 o[2][4] = {};
    #pragma unroll
    for (int ks = 0; ks < 128; ks += 32) {
        bf16x8 ap[2];
        #pragma unroll
        for (int i = 0; i < 2; ++i)
            ap[i] = *reinterpret_cast<const bf16x8*>(&P_lds[(wq + i * 16 + lm) * 136 + ks + quad * 8]);
        #pragma unroll
        for (int n = 0; n < 4; ++n) {
            bf16x8 bv = *reinterpret_cast<const bf16x8*>(&vt_lds[(n * 16 + lm) * 136 + ks + quad * 8]);
            o[0][n] = mfma16(ap[0], bv, o[0][n]);
            o[1][n] = mfma16(ap[1], bv, o[1][n]);
        }
    }
    #pragma unroll
    for (int i = 0; i < 2; ++i)
        #pragma unroll
        for (int reg = 0; reg < 4; ++reg) {
            int row = wq + i * 16 + quad * 4 + reg;
            #pragma unroll
            for (int n = 0; n < 4; ++n)
                Qkv[(size_t)(g0 + row) * NQKV + hc + n * 16 + lm] = f2b(o[i][n][reg]);
        }
}

// ---------------------------------------------------------------------------
// Fused output projection + bias + residual + LayerNorm -> fp32 out (once).
// BM=128, BN=768 (full row in-block), 1024 threads = 16 waves (2M x 8N),
// wave tile 64x96, acc[4][6]. K=768 in 24 BK=32 tiles.
// LDS: A[2][128][64] (pair-of-tiles dbuf, 32KB), B[2][768][32] (96KB),
// red[128][18] (9KB). Per tile t: stage B(t+1) (3 gloads) + A(pair+1) at even
// t (1 gload). Boundary waits (before trailing barrier, race-safe):
// even t<22 -> vwait<1> (keep A in flight); else vwait<0>.
// B-frag reads split 3+3 around MFMA to stay under the 128-VGPR cap.
// ---------------------------------------------------------------------------
__global__ __launch_bounds__(1024, 4) void k_oproj_ln(
    const bf16* __restrict__ Aq, const bf16* __restrict__ WoT,
    const float* __restrict__ bo, const float* __restrict__ X,
    const float* __restrict__ ln_g, const float* __restrict__ ln_b,
    float* __restrict__ out, int tok0)
{
    __shared__ alignas(16) bf16 a_lds[2 * 128 * 64];   // 32 KiB
    __shared__ alignas(16) bf16 b_lds[2 * 768 * 32];   // 96 KiB
    __shared__ float red[128][18];                      // 9 KiB

    const int tid = threadIdx.x;
    const int wave = tid >> 6, lane = tid & 63, quad = lane >> 4, lm = lane & 15;
    const int wm = wave >> 3, wn = wave & 7;           // 2M x 8N
    const int blk128 = blockIdx.x * 128;

    // staging lane mapping
    const int asl = ((tid & 7) ^ ((tid >> 3) & 7)) * 8;   // A: 128B rows
    const int bsl = ((tid & 3) ^ ((tid >> 2) & 3)) * 8;   // B: 64B rows
    const bf16* a_srcp = Aq + (size_t)(blk128 + (tid >> 3)) * NQKV + asl;

    auto stageAo = [&](int P) {    // A pair P: [128][64] = 16KB, one call
        bf16* d = a_lds + (P & 1) * 8192 + wave * 512;
        gload_lds16(a_srcp + P * 64, d);
    };
    auto stageBo = [&](int T, int c) {   // B rows c*256..c*256+255 of tile T
        bf16* d = b_lds + (T & 1) * 24576 + c * 8192 + wave * 512;
        const bf16* s = WoT + (size_t)(c * 256 + (tid >> 2)) * D + T * 32 + bsl;
        gload_lds16(s, d);
    };

    // fragment slots
    const int swA0 = ((0 + quad) ^ (lm & 7)) * 8;   // tt = 0
    const int swA1 = ((4 + quad) ^ (lm & 7)) * 8;   // tt = 1
    const int swB  = (quad ^ (lm & 3)) * 8;
    const int arow = wm * 64 + lm;                  // + i*16
    const int brow = wn * 96 + lm;                  // + n*16

    f32x4 acc[4][6] = {};

    // prologue: tile0 B (3) + pair0 A (1); drain, barrier.
    stageBo(0, 0); stageBo(0, 1); stageBo(0, 2); stageAo(0);
    vwait<0>();
    __builtin_amdgcn_s_barrier();

    #pragma unroll
    for (int t = 0; t < 24; ++t) {
        const bf16* ab = a_lds + ((t >> 1) & 1) * 8192;
        const bf16* bb = b_lds + (t & 1) * 24576;
        const int swA = (t & 1) ? swA1 : swA0;
        bf16x8 af[4], bf0[3];
        #pragma unroll
        for (int i = 0; i < 4; ++i)
            af[i] = *reinterpret_cast<const bf16x8*>(&ab[(arow + i * 16) * 64 + swA]);
        #pragma unroll
        for (int n = 0; n < 3; ++n)
            bf0[n] = *reinterpret_cast<const bf16x8*>(&bb[(brow + n * 16) * 32 + swB]);
        if (t + 1 < 24) { stageBo(t + 1, 0); stageBo(t + 1, 1); stageBo(t + 1, 2); }
        if ((t & 1) == 0 && (t >> 1) + 1 < 12) stageAo((t >> 1) + 1);
        __builtin_amdgcn_s_barrier();
        lgkm0();
        __builtin_amdgcn_s_setprio(1);
        #pragma unroll
        for (int i = 0; i < 4; ++i)
            #pragma unroll
            for (int n = 0; n < 3; ++n)
                acc[i][n] = mfma16(af[i], bf0[n], acc[i][n]);
        bf16x8 bf1[3];
        #pragma unroll
        for (int n = 0; n < 3; ++n)
            bf1[n] = *reinterpret_cast<const bf16x8*>(&bb[(brow + (n + 3) * 16) * 32 + swB]);
        #pragma unroll
        for (int i = 0; i < 4; ++i)
            #pragma unroll
            for (int n = 0; n < 3; ++n)
                acc[i][n + 3] = mfma16(af[i], bf1[n], acc[i][n + 3]);
        __builtin_amdgcn_s_setprio(0);
        // ---- boundary: counted wait BEFORE trailing barrier (race-safe) ----
        if (t < 23) {
            if ((t & 1) == 0 && t < 22) vwait<1>(); else vwait<0>();
            __builtin_amdgcn_s_barrier();
        }
    }

    // ---- epilogue: bias + residual, then in-block LayerNorm ----
    float bov[6], gv[6], bbv[6];
    #pragma unroll
    for (int n = 0; n < 6; ++n) {
        int c = wn * 96 + n * 16 + lm;
        bov[n] = bo[c]; gv[n] = ln_g[c]; bbv[n] = ln_b[c];
    }

    #pragma unroll
    for (int i = 0; i < 4; ++i)
        #pragma unroll
        for (int reg = 0; reg < 4; ++reg) {
            int r = wm * 64 + i * 16 + quad * 4 + reg;
            int gt = tok0 + blk128 + r, b = gt >> 13, pos = gt & 8191;
            bool live = pos < LSEQ;
            size_t xrow = ((size_t)b * LSEQ + pos) * D;
            float s = 0.f, sq = 0.f;
            #pragma unroll
            for (int n = 0; n < 6; ++n) {
                int c = wn * 96 + n * 16 + lm;
                float y = acc[i][n][reg] + bov[n] + (live ? X[xrow + c] : 0.f);
                acc[i][n][reg] = y;          // keep y in place for pass 2
                s += y; sq += y * y;
            }
            #pragma unroll
            for (int off = 1; off <= 8; off <<= 1) {
                s  += __shfl_xor(s, off);
                sq += __shfl_xor(sq, off);
            }
            if (lm == 0) { red[r][wn] = s; red[r][8 + wn] = sq; }
        }
    __syncthreads();
    if (tid < 128) {
        float s = 0.f, sq = 0.f;
        #pragma unroll
        for (int w = 0; w < 8; ++w) { s += red[tid][w]; sq += red[tid][8 + w]; }
        float mu = s * (1.f / 768.f);
        float var = sq * (1.f / 768.f) - mu * mu;
        red[tid][16] = mu;
        red[tid][17] = rsqrtf(var + 1e-5f);
    }
    __syncthreads();

    #pragma unroll
    for (int i = 0; i < 4; ++i)
        #pragma unroll
        for (int reg = 0; reg < 4; ++reg) {
            int r = wm * 64 + i * 16 + quad * 4 + reg;
            int gt = tok0 + blk128 + r, b = gt >> 13, pos = gt & 8191;
            if (pos >= LSEQ) continue;       // crop pad rows
            size_t orow = ((size_t)b * LSEQ + pos) * D;
            float mu = red[r][16], rs = red[r][17];
            #pragma unroll
            for (int n = 0; n < 6; ++n) {
                int c = wn * 96 + n * 16 + lm;
                out[orow + c] = (acc[i][n][reg] - mu) * rs * gv[n] + bbv[n];
            }
        }
}

// ---------------------------------------------------------------------------
extern "C" void kernel_launch(void* const* d_in, const int* in_sizes, int n_in,
                              void* d_out, int out_size, void* d_ws, size_t ws_size,
                              hipStream_t stream)
{
    const float* expanded = (const float*)d_in[0];
    const float* Wq = (const float*)d_in[1];
    const float* bq = (const float*)d_in[2];
    const float* Wk = (const float*)d_in[3];
    const float* bk = (const float*)d_in[4];
    const float* Wv = (const float*)d_in[5];
    const float* bv = (const float*)d_in[6];
    const float* Wo = (const float*)d_in[7];
    const float* bo = (const float*)d_in[8];
    const float* ln_g = (const float*)d_in[9];
    const float* ln_b = (const float*)d_in[10];
    float* out = (float*)d_out;

    char* ws = (char*)d_ws;
    const size_t WSZ = (size_t)D * D * sizeof(bf16);     // 1.18 MB
    bf16* WqkvT = (bf16*)(ws);                           // 3 slices
    bf16* WoT   = (bf16*)(ws + 3 * WSZ);
    const size_t fixed = 4 * WSZ;

    // Largest token-chunk fitting the workspace (multiple of 256 for 256-row tiles)
    int cht = TP;
    while (cht > 256 && fixed + (size_t)cht * (D + NQKV) * sizeof(bf16) > ws_size)
        cht >>= 1;
    bf16* Xb  = (bf16*)(ws + fixed);
    bf16* Qkv = (bf16*)(ws + fixed + (size_t)cht * D * sizeof(bf16));

    k_transpose<<<dim3((D * D) / 256, 4), 256, 0, stream>>>(Wq, Wk, Wv, Wo, WqkvT, WoT);

    for (int t0 = 0; t0 < TP; t0 += cht) {
        k_prep<<<(cht * D) / 2048, 256, 0, stream>>>(expanded, Xb, t0);
        k_gemm_qkv<<<dim3((cht / 256) * 9), 512, 0, stream>>>(
            Xb, WqkvT, bq, bk, bv, Qkv);
        k_attn<<<dim3(cht / 128, NH), 256, 0, stream>>>(Qkv);
        k_oproj_ln<<<dim3(cht / 128), 1024, 0, stream>>>(
            Qkv, WoT, bo, expanded, ln_g, ln_b, out, t0);
    }
}

// Round 4
// 500.017 us; speedup vs baseline: 1.2180x; 1.2180x over previous
//
#include <hip/hip_runtime.h>
#include <hip/hip_bf16.h>

#define D 768
#define NQKV 2304            /* 3*D */
#define NH 12
#define HD 64
#define BATCH 4
#define LSEQ 8190
#define LPAD 8192
#define TP (BATCH*LPAD)      /* 32768 padded tokens */

typedef __bf16 bf16x8 __attribute__((ext_vector_type(8)));
typedef float f32x4 __attribute__((ext_vector_type(4)));
using bf16 = __hip_bfloat16;

__device__ __forceinline__ float b2f(bf16 x){ return __bfloat162float(x); }
__device__ __forceinline__ bf16 f2b(float x){ return __float2bfloat16(x); }
__device__ __forceinline__ f32x4 mfma16(bf16x8 a, bf16x8 b, f32x4 c){
    return __builtin_amdgcn_mfma_f32_16x16x32_bf16(a, b, c, 0, 0, 0);
}
// async global->LDS, 16 B per lane; LDS dest = wave-uniform base + lane*16
__device__ __forceinline__ void gload_lds16(const void* g, void* l){
    __builtin_amdgcn_global_load_lds(
        (const __attribute__((address_space(1))) unsigned int*)g,
        (__attribute__((address_space(3))) unsigned int*)l, 16, 0, 0);
}
template<int N> __device__ __forceinline__ void vwait(){
    asm volatile("s_waitcnt vmcnt(%0)" :: "n"(N) : "memory");
}
__device__ __forceinline__ void lgkm0(){
    asm volatile("s_waitcnt lgkmcnt(0)" ::: "memory");
}

// ---------------------------------------------------------------------------
// Transpose+convert fp32 weights -> bf16 [n][k]. y=0..2 -> WqkvT slices, y=3 -> WoT.
// ---------------------------------------------------------------------------
__global__ void k_transpose(const float* __restrict__ w0, const float* __restrict__ w1,
                            const float* __restrict__ w2, const float* __restrict__ w3,
                            bf16* __restrict__ WqkvT, bf16* __restrict__ WoT) {
    const float* src; bf16* dst;
    switch (blockIdx.y) {
        case 0:  src = w0; dst = WqkvT;               break;
        case 1:  src = w1; dst = WqkvT + D * D;       break;
        case 2:  src = w2; dst = WqkvT + 2 * D * D;   break;
        default: src = w3; dst = WoT;                 break;
    }
    int o = blockIdx.x * 256 + threadIdx.x;   // 0..589823
    int n = o / D, k = o % D;
    dst[o] = f2b(src[k * D + n]);             // dst[n][k] = src[k][n]
}

// ---------------------------------------------------------------------------
// Convert chunk of X (global padded-token indexed) to bf16, pad rows -> 0.
// ---------------------------------------------------------------------------
__global__ __launch_bounds__(256) void k_prep(const float* __restrict__ X,
                                              bf16* __restrict__ Xb, int tok0)
{
    int idx = (blockIdx.x * 256 + threadIdx.x) * 8;  // chunk-local elem
    int row = idx / D, col = idx % D;
    int gt = tok0 + row, b = gt >> 13, pos = gt & 8191;
    bf16 tmp[8];
    if (pos < LSEQ) {
        const float* s = &X[((size_t)b * LSEQ + pos) * D + col];
        float4 f0 = *reinterpret_cast<const float4*>(s);
        float4 f1 = *reinterpret_cast<const float4*>(s + 4);
        tmp[0]=f2b(f0.x); tmp[1]=f2b(f0.y); tmp[2]=f2b(f0.z); tmp[3]=f2b(f0.w);
        tmp[4]=f2b(f1.x); tmp[5]=f2b(f1.y); tmp[6]=f2b(f1.z); tmp[7]=f2b(f1.w);
    } else {
        #pragma unroll
        for (int j = 0; j < 8; ++j) tmp[j] = f2b(0.f);
    }
    *reinterpret_cast<uint4*>(&Xb[idx]) = *reinterpret_cast<const uint4*>(tmp);
}

// ---------------------------------------------------------------------------
// Fused QKV GEMM, 256x256 tile, BK=64, 8 waves (2Mx4N), wave C = 128x64.
// LDS: A[2][256][64], B[2][256][64] (128 KiB dbuf). 4 phases/K-tile, 16 MFMA
// each, B-frags hoisted at p0.
//
// RACE-SAFE BOUNDARY RULE: vmcnt is per-wave, so every counted wait sits
// BEFORE a trailing s_barrier; only data covered by a prior
// {all-waves vwait + barrier} is ever ds_read. Boundaries:
//   end p1: vwait<4> (retire cur tile A-h1; keep next-tile B stages in flight)
//   end p3: vwait<2> (retire next tile B-h0,B-h1,A-h0; keep A-h1 in flight)
//   last tile: vwait<0> at p1.
// Swizzle: 16B slot s of a 128B row r holds global slot s ^ (r&7), applied on
// the global source (gload_lds writes linearly) and on the ds_read address.
// ---------------------------------------------------------------------------
__global__ __launch_bounds__(512, 2) void k_gemm_qkv(
    const bf16* __restrict__ Xb, const bf16* __restrict__ Wt,
    const float* __restrict__ bq, const float* __restrict__ bk, const float* __restrict__ bv,
    bf16* __restrict__ Qkv)
{
    __shared__ alignas(16) bf16 a_lds[2 * 256 * 64];   // 64 KiB
    __shared__ alignas(16) bf16 b_lds[2 * 256 * 64];   // 64 KiB

    const int tid = threadIdx.x;
    const int wave = tid >> 6, lane = tid & 63, quad = lane >> 4, lm = lane & 15;
    const int wm = wave >> 2, wn = wave & 3;           // 2x4 wave grid

    // XCD-aware bijective swizzle (nwg % 8 == 0 in all chunk configs used)
    int bid = blockIdx.x;
    const int nwg = gridDim.x;
    if ((nwg & 7) == 0) { const int cpx = nwg >> 3; bid = (bid & 7) * cpx + (bid >> 3); }
    const int rt = bid / 9, ct = bid % 9;

    // staging: one gload call = 512 lanes x 16B = 8KB = 64 rows x 128B
    const int srow = tid >> 3;                         // 0..63
    const int ssl  = ((tid & 7) ^ (srow & 7)) * 8;     // pre-swizzled k-slot
    const bf16* a_src = Xb + (size_t)(rt * 256 + srow) * D + ssl;
    const bf16* b_src = Wt + (size_t)(ct * 256 + srow) * D + ssl;
    const int ldsW = wave * 512;                       // wave-uniform dest (elems)

    auto stageA = [&](int T, int h) {                  // rows h*128 .. h*128+127
        bf16* d = a_lds + (T & 1) * 16384 + h * 8192 + ldsW;
        const bf16* s = a_src + (size_t)(h * 128) * D + T * 64;
        gload_lds16(s, d);
        gload_lds16(s + (size_t)64 * D, d + 4096);
    };
    auto stageB = [&](int T, int h) {
        bf16* d = b_lds + (T & 1) * 16384 + h * 8192 + ldsW;
        const bf16* s = b_src + (size_t)(h * 128) * D + T * 64;
        gload_lds16(s, d);
        gload_lds16(s + (size_t)64 * D, d + 4096);
    };

    // swizzled fragment slots (row&7 == lm&7 for all frag rows)
    const int swf0 = ((0 + quad) ^ (lm & 7)) * 8;      // ks = 0
    const int swf1 = ((4 + quad) ^ (lm & 7)) * 8;      // ks = 1
    const int arow0 = wm * 32 + lm;
    const int brow0 = wn * 64 + lm;

    f32x4 acc[8][4] = {};

    // prologue: stage tile 0 (8 loads, order Bh0,Bh1,Ah0,Ah1); retire first 6.
    stageB(0, 0); stageB(0, 1); stageA(0, 0); stageA(0, 1);
    vwait<2>();
    __builtin_amdgcn_s_barrier();

    #pragma unroll
    for (int t = 0; t < 12; ++t) {
        const bf16* ab = a_lds + (t & 1) * 16384;
        const bf16* bb = b_lds + (t & 1) * 16384;
        bf16x8 bfr[4][2];
        #pragma unroll
        for (int p = 0; p < 4; ++p) {
            // ---- fragment ds_reads (covered by earlier vwait+barrier) ----
            bf16x8 af[2][2];
            #pragma unroll
            for (int i = 0; i < 2; ++i) {
                const int r = (p * 64 + arow0 + i * 16) * 64;
                af[i][0] = *reinterpret_cast<const bf16x8*>(&ab[r + swf0]);
                af[i][1] = *reinterpret_cast<const bf16x8*>(&ab[r + swf1]);
            }
            if (p == 0) {
                #pragma unroll
                for (int n = 0; n < 4; ++n) {
                    const int r = (brow0 + n * 16) * 64;
                    bfr[n][0] = *reinterpret_cast<const bf16x8*>(&bb[r + swf0]);
                    bfr[n][1] = *reinterpret_cast<const bf16x8*>(&bb[r + swf1]);
                }
            }
            // ---- stage next tile (other buffer; 2 gloads per phase) ----
            if (t < 11) {
                if (p == 0) stageB(t + 1, 0);
                if (p == 1) stageB(t + 1, 1);
                if (p == 2) stageA(t + 1, 0);
                if (p == 3) stageA(t + 1, 1);
            }
            __builtin_amdgcn_s_barrier();
            lgkm0();
            __builtin_amdgcn_s_setprio(1);
            #pragma unroll
            for (int ks = 0; ks < 2; ++ks)
                #pragma unroll
                for (int i = 0; i < 2; ++i)
                    #pragma unroll
                    for (int n = 0; n < 4; ++n)
                        acc[p * 2 + i][n] = mfma16(af[i][ks], bfr[n][ks], acc[p * 2 + i][n]);
            __builtin_amdgcn_s_setprio(0);
            // ---- boundary waits: BEFORE the trailing barrier ----
            if (p == 1) { if (t < 11) vwait<4>(); else vwait<0>(); }
            if (p == 3 && t < 11) vwait<2>();
            if (!(p == 3 && t == 11)) __builtin_amdgcn_s_barrier();
        }
    }

    // epilogue: bias + bf16 store. ct*256 block lies inside one of q/k/v.
    const float* bias; int cb;
    if (ct < 3)      { bias = bq; cb = ct * 256; }
    else if (ct < 6) { bias = bk; cb = ct * 256 - D; }
    else             { bias = bv; cb = ct * 256 - 2 * D; }
    float bvv[4];
    #pragma unroll
    for (int n = 0; n < 4; ++n)
        bvv[n] = bias[cb + wn * 64 + n * 16 + lm];

    const int col0 = ct * 256 + wn * 64 + lm;
    #pragma unroll
    for (int j = 0; j < 8; ++j)
        #pragma unroll
        for (int reg = 0; reg < 4; ++reg) {
            int row = rt * 256 + (j >> 1) * 64 + wm * 32 + (j & 1) * 16 + quad * 4 + reg;
            size_t rb = (size_t)row * NQKV;
            #pragma unroll
            for (int n = 0; n < 4; ++n)
                Qkv[rb + col0 + n * 16] = f2b(acc[j][n][reg] + bvv[n]);
        }
}

// ---------------------------------------------------------------------------
// Per-(window, head) attention on the interleaved Qkv buffer (stride 2304).
// ---------------------------------------------------------------------------
__global__ __launch_bounds__(256) void k_attn(bf16* Qkv)
{
    __shared__ bf16 qk_lds[2 * 128 * 72];
    __shared__ bf16 vt_lds[64 * 136];
    const int tid = threadIdx.x;
    const int g0 = blockIdx.x * 128, hc = blockIdx.y * 64;
    const int wave = tid >> 6, lane = tid & 63, quad = lane >> 4, lm = lane & 15;
    const int wq = wave * 32;
    bf16* Q_lds = qk_lds;
    bf16* K_lds = qk_lds + 128 * 72;
    bf16* P_lds = qk_lds;                   // overlay after barrier, stride 136

    #pragma unroll
    for (int p = 0; p < 4; ++p) {
        int cid = tid + p * 256;            // 0..1023
        int r = cid >> 3, cc = (cid & 7) * 8;
        size_t rb = (size_t)(g0 + r) * NQKV;
        *reinterpret_cast<uint4*>(&Q_lds[r * 72 + cc]) =
            *reinterpret_cast<const uint4*>(&Qkv[rb + hc + cc]);
        *reinterpret_cast<uint4*>(&K_lds[r * 72 + cc]) =
            *reinterpret_cast<const uint4*>(&Qkv[rb + D + hc + cc]);
        uint4 vv = *reinterpret_cast<const uint4*>(&Qkv[rb + 2 * D + hc + cc]);
        const bf16* ve = reinterpret_cast<const bf16*>(&vv);
        #pragma unroll
        for (int j = 0; j < 8; ++j) vt_lds[(cc + j) * 136 + r] = ve[j];   // V^T
    }
    __syncthreads();

    // S = Q K^T : each wave computes 32 query rows x 128 keys
    f32x4 s[2][8] = {};
    #pragma unroll
    for (int ks = 0; ks < HD; ks += 32) {
        bf16x8 aq[2];
        #pragma unroll
        for (int i = 0; i < 2; ++i)
            aq[i] = *reinterpret_cast<const bf16x8*>(&Q_lds[(wq + i * 16 + lm) * 72 + ks + quad * 8]);
        #pragma unroll
        for (int nt = 0; nt < 8; ++nt) {
            bf16x8 bk = *reinterpret_cast<const bf16x8*>(&K_lds[(nt * 16 + lm) * 72 + ks + quad * 8]);
            s[0][nt] = mfma16(aq[0], bk, s[0][nt]);
            s[1][nt] = mfma16(aq[1], bk, s[1][nt]);
        }
    }
    __syncthreads();   // all Q/K reads done before P overlays them

    const float scale = 0.125f;             // 1/sqrt(64)
    #pragma unroll
    for (int i = 0; i < 2; ++i)
        #pragma unroll
        for (int reg = 0; reg < 4; ++reg) {
            float m = -1e30f;
            #pragma unroll
            for (int nt = 0; nt < 8; ++nt) m = fmaxf(m, s[i][nt][reg]);
            #pragma unroll
            for (int off = 8; off >= 1; off >>= 1) m = fmaxf(m, __shfl_xor(m, off));
            float pv[8]; float sum = 0.f;
            #pragma unroll
            for (int nt = 0; nt < 8; ++nt) {
                float p = __expf((s[i][nt][reg] - m) * scale);
                pv[nt] = p; sum += p;
            }
            #pragma unroll
            for (int off = 8; off >= 1; off >>= 1) sum += __shfl_xor(sum, off);
            float rinv = 1.f / sum;
            int row = wq + i * 16 + quad * 4 + reg;
            #pragma unroll
            for (int nt = 0; nt < 8; ++nt)
                P_lds[row * 136 + nt * 16 + lm] = f2b(pv[nt] * rinv);
        }
    __syncthreads();

    // O = P V
    f32x4 o[2][4] = {};
    #pragma unroll
    for (int ks = 0; ks < 128; ks += 32) {
        bf16x8 ap[2];
        #pragma unroll
        for (int i = 0; i < 2; ++i)
            ap[i] = *reinterpret_cast<const bf16x8*>(&P_lds[(wq + i * 16 + lm) * 136 + ks + quad * 8]);
        #pragma unroll
        for (int n = 0; n < 4; ++n) {
            bf16x8 bv = *reinterpret_cast<const bf16x8*>(&vt_lds[(n * 16 + lm) * 136 + ks + quad * 8]);
            o[0][n] = mfma16(ap[0], bv, o[0][n]);
            o[1][n] = mfma16(ap[1], bv, o[1][n]);
        }
    }
    #pragma unroll
    for (int i = 0; i < 2; ++i)
        #pragma unroll
        for (int reg = 0; reg < 4; ++reg) {
            int row = wq + i * 16 + quad * 4 + reg;
            #pragma unroll
            for (int n = 0; n < 4; ++n)
                Qkv[(size_t)(g0 + row) * NQKV + hc + n * 16 + lm] = f2b(o[i][n][reg]);
        }
}

// ---------------------------------------------------------------------------
// Fused output projection + bias + residual + LayerNorm -> fp32 out (once).
// BM=64, BN=768 (full row in-block), 512 threads = 8 waves (1M x 8N),
// wave tile 64x96, acc[4][6] = 96 VGPR. 8-wave block => 2 waves/SIMD =>
// VGPR cap 256 (round-3 used 16-wave blocks: hard cap 128 -> spilled).
// K=768 in 24 BK=32 tiles; A staged in BK=64 pairs.
// LDS: A[2][64][64] (16KB), B[2][768][32] (96KB dbuf), red[64][18] (4.5KB).
// Per tile t: stage B(t+1) (6 gloads, 128 rows each) + A(pair+1) at even t
// (1 gload). Race-safe boundary (wait BEFORE trailing barrier):
// even t<22 -> vwait<1> (A stays in flight; it is read 2 tiles later);
// otherwise vwait<0>.
// ---------------------------------------------------------------------------
__global__ __launch_bounds__(512, 1) void k_oproj_ln(
    const bf16* __restrict__ Aq, const bf16* __restrict__ WoT,
    const float* __restrict__ bo, const float* __restrict__ X,
    const float* __restrict__ ln_g, const float* __restrict__ ln_b,
    float* __restrict__ out, int tok0)
{
    __shared__ alignas(16) bf16 a_lds[2 * 64 * 64];    // 16 KiB
    __shared__ alignas(16) bf16 b_lds[2 * 768 * 32];   // 96 KiB
    __shared__ float red[64][18];                       // 4.5 KiB

    const int tid = threadIdx.x;
    const int wave = tid >> 6, lane = tid & 63, quad = lane >> 4, lm = lane & 15;
    const int wn = wave;                                // 1M x 8N
    const int blk64 = blockIdx.x * 64;

    // staging lane mappings (512 threads)
    // A: 64 rows x 128B; row = tid>>3, chunk = tid&7, swizzle chunk^(row&7)
    const int asl = ((tid & 7) ^ ((tid >> 3) & 7)) * 8;
    const bf16* a_srcp = Aq + (size_t)(blk64 + (tid >> 3)) * NQKV + asl;
    // B: 128 rows x 64B per gload; row = c*128 + (tid>>2), slot = tid&3,
    // swizzle slot^(row&3) with row&3 == (tid>>2)&3
    const int bsl = ((tid & 3) ^ ((tid >> 2) & 3)) * 8;

    auto stageAo = [&](int P) {    // A pair P: [64][64] = 8KB, one gload
        bf16* d = a_lds + (P & 1) * 4096 + wave * 512;
        gload_lds16(a_srcp + P * 64, d);
    };
    auto stageBo = [&](int T, int c) {   // B rows c*128..c*128+127 of tile T
        bf16* d = b_lds + (T & 1) * 24576 + c * 4096 + wave * 512;
        const bf16* s = WoT + (size_t)(c * 128 + (tid >> 2)) * D + T * 32 + bsl;
        gload_lds16(s, d);
    };

    // fragment slots
    const int swA0 = ((0 + quad) ^ (lm & 7)) * 8;   // K-half 0 of pair
    const int swA1 = ((4 + quad) ^ (lm & 7)) * 8;   // K-half 1 of pair
    const int swB  = (quad ^ (lm & 3)) * 8;
    const int arow = lm;                            // + i*16
    const int brow = wn * 96 + lm;                  // + n*16

    f32x4 acc[4][6] = {};

    // prologue: tile0 B (6) + pair0 A (1); drain, barrier.
    stageBo(0, 0); stageBo(0, 1); stageBo(0, 2);
    stageBo(0, 3); stageBo(0, 4); stageBo(0, 5);
    stageAo(0);
    vwait<0>();
    __builtin_amdgcn_s_barrier();

    #pragma unroll
    for (int t = 0; t < 24; ++t) {
        const bf16* ab = a_lds + ((t >> 1) & 1) * 4096;
        const bf16* bb = b_lds + (t & 1) * 24576;
        const int swA = (t & 1) ? swA1 : swA0;
        bf16x8 af[4], bf0[3];
        #pragma unroll
        for (int i = 0; i < 4; ++i)
            af[i] = *reinterpret_cast<const bf16x8*>(&ab[(arow + i * 16) * 64 + swA]);
        #pragma unroll
        for (int n = 0; n < 3; ++n)
            bf0[n] = *reinterpret_cast<const bf16x8*>(&bb[(brow + n * 16) * 32 + swB]);
        if (t + 1 < 24) {
            stageBo(t + 1, 0); stageBo(t + 1, 1); stageBo(t + 1, 2);
            stageBo(t + 1, 3); stageBo(t + 1, 4); stageBo(t + 1, 5);
        }
        if ((t & 1) == 0 && (t >> 1) + 1 < 12) stageAo((t >> 1) + 1);
        __builtin_amdgcn_s_barrier();
        lgkm0();
        __builtin_amdgcn_s_setprio(1);
        #pragma unroll
        for (int i = 0; i < 4; ++i)
            #pragma unroll
            for (int n = 0; n < 3; ++n)
                acc[i][n] = mfma16(af[i], bf0[n], acc[i][n]);
        bf16x8 bf1[3];
        #pragma unroll
        for (int n = 0; n < 3; ++n)
            bf1[n] = *reinterpret_cast<const bf16x8*>(&bb[(brow + (n + 3) * 16) * 32 + swB]);
        #pragma unroll
        for (int i = 0; i < 4; ++i)
            #pragma unroll
            for (int n = 0; n < 3; ++n)
                acc[i][n + 3] = mfma16(af[i], bf1[n], acc[i][n + 3]);
        __builtin_amdgcn_s_setprio(0);
        // ---- boundary: counted wait BEFORE trailing barrier (race-safe) ----
        if (t < 23) {
            if ((t & 1) == 0 && t < 22) vwait<1>(); else vwait<0>();
            __builtin_amdgcn_s_barrier();
        }
    }

    // ---- epilogue: bias + residual, then in-block LayerNorm ----
    float bov[6], gv[6], bbv[6];
    #pragma unroll
    for (int n = 0; n < 6; ++n) {
        int c = wn * 96 + n * 16 + lm;
        bov[n] = bo[c]; gv[n] = ln_g[c]; bbv[n] = ln_b[c];
    }

    #pragma unroll
    for (int i = 0; i < 4; ++i)
        #pragma unroll
        for (int reg = 0; reg < 4; ++reg) {
            int r = i * 16 + quad * 4 + reg;
            int gt = tok0 + blk64 + r, b = gt >> 13, pos = gt & 8191;
            bool live = pos < LSEQ;
            size_t xrow = ((size_t)b * LSEQ + pos) * D;
            float s = 0.f, sq = 0.f;
            #pragma unroll
            for (int n = 0; n < 6; ++n) {
                int c = wn * 96 + n * 16 + lm;
                float y = acc[i][n][reg] + bov[n] + (live ? X[xrow + c] : 0.f);
                acc[i][n][reg] = y;          // keep y in place for pass 2
                s += y; sq += y * y;
            }
            #pragma unroll
            for (int off = 1; off <= 8; off <<= 1) {
                s  += __shfl_xor(s, off);
                sq += __shfl_xor(sq, off);
            }
            if (lm == 0) { red[r][wn] = s; red[r][8 + wn] = sq; }
        }
    __syncthreads();
    if (tid < 64) {
        float s = 0.f, sq = 0.f;
        #pragma unroll
        for (int w = 0; w < 8; ++w) { s += red[tid][w]; sq += red[tid][8 + w]; }
        float mu = s * (1.f / 768.f);
        float var = sq * (1.f / 768.f) - mu * mu;
        red[tid][16] = mu;
        red[tid][17] = rsqrtf(var + 1e-5f);
    }
    __syncthreads();

    #pragma unroll
    for (int i = 0; i < 4; ++i)
        #pragma unroll
        for (int reg = 0; reg < 4; ++reg) {
            int r = i * 16 + quad * 4 + reg;
            int gt = tok0 + blk64 + r, b = gt >> 13, pos = gt & 8191;
            if (pos >= LSEQ) continue;       // crop pad rows
            size_t orow = ((size_t)b * LSEQ + pos) * D;
            float mu = red[r][16], rs = red[r][17];
            #pragma unroll
            for (int n = 0; n < 6; ++n) {
                int c = wn * 96 + n * 16 + lm;
                out[orow + c] = (acc[i][n][reg] - mu) * rs * gv[n] + bbv[n];
            }
        }
}

// ---------------------------------------------------------------------------
extern "C" void kernel_launch(void* const* d_in, const int* in_sizes, int n_in,
                              void* d_out, int out_size, void* d_ws, size_t ws_size,
                              hipStream_t stream)
{
    const float* expanded = (const float*)d_in[0];
    const float* Wq = (const float*)d_in[1];
    const float* bq = (const float*)d_in[2];
    const float* Wk = (const float*)d_in[3];
    const float* bk = (const float*)d_in[4];
    const float* Wv = (const float*)d_in[5];
    const float* bv = (const float*)d_in[6];
    const float* Wo = (const float*)d_in[7];
    const float* bo = (const float*)d_in[8];
    const float* ln_g = (const float*)d_in[9];
    const float* ln_b = (const float*)d_in[10];
    float* out = (float*)d_out;

    char* ws = (char*)d_ws;
    const size_t WSZ = (size_t)D * D * sizeof(bf16);     // 1.18 MB
    bf16* WqkvT = (bf16*)(ws);                           // 3 slices
    bf16* WoT   = (bf16*)(ws + 3 * WSZ);
    const size_t fixed = 4 * WSZ;

    // Largest token-chunk fitting the workspace (multiple of 256 for 256-row tiles)
    int cht = TP;
    while (cht > 256 && fixed + (size_t)cht * (D + NQKV) * sizeof(bf16) > ws_size)
        cht >>= 1;
    bf16* Xb  = (bf16*)(ws + fixed);
    bf16* Qkv = (bf16*)(ws + fixed + (size_t)cht * D * sizeof(bf16));

    k_transpose<<<dim3((D * D) / 256, 4), 256, 0, stream>>>(Wq, Wk, Wv, Wo, WqkvT, WoT);

    for (int t0 = 0; t0 < TP; t0 += cht) {
        k_prep<<<(cht * D) / 2048, 256, 0, stream>>>(expanded, Xb, t0);
        k_gemm_qkv<<<dim3((cht / 256) * 9), 512, 0, stream>>>(
            Xb, WqkvT, bq, bk, bv, Qkv);
        k_attn<<<dim3(cht / 128, NH), 256, 0, stream>>>(Qkv);
        k_oproj_ln<<<dim3(cht / 64), 512, 0, stream>>>(
            Qkv, WoT, bo, expanded, ln_g, ln_b, out, t0);
    }
}